// Round 14
// baseline (128.941 us; speedup 1.0000x reference)
//
#include <hip/hip_runtime.h>

#define NB_ 3
#define CB 4
#define CH 1440
#define CW 1440
#define NC 32
#define EPSV 1e-3f

typedef __attribute__((ext_vector_type(8))) short bf16x8;
typedef __attribute__((ext_vector_type(16))) float f32x16;

union U16 { uint4 u; bf16x8 v; };

__device__ __forceinline__ unsigned pk2(float a, float b) {
    unsigned ua = __float_as_uint(a), ub = __float_as_uint(b);
    ua += 0x7fffu + ((ua >> 16) & 1u);
    ub += 0x7fffu + ((ub >> 16) & 1u);
    return (ua >> 16) | (ub & 0xffff0000u);
}
__device__ __forceinline__ float bfl(unsigned u) { return __uint_as_float(u << 16); }
__device__ __forceinline__ float bfh(unsigned u) { return __uint_as_float(u & 0xffff0000u); }

// ---------------- kernel 0: clear ONLY center cells + emit packed keys -------------
// (r13 logic: neighbor cells verified at query time, multi-point cells always
// cleared+rebuilt, stale winners idempotent -> replay-deterministic.)
__global__ __launch_bounds__(256) void k_clear(
    const int* __restrict__ cb, const int* __restrict__ cy, const int* __restrict__ cx,
    int* __restrict__ idx_map, unsigned* __restrict__ pkey, int n)
{
    int i = blockIdx.x * blockDim.x + threadIdx.x;
    if (i >= n) return;
    unsigned key = ((unsigned)cb[i] * CH + (unsigned)cy[i]) * CW + (unsigned)cx[i];
    pkey[i] = key;
    idx_map[key] = -1;
}

// ---------------- kernel 1: build idx_map via atomicMax (numpy last-write-wins) ----
__global__ __launch_bounds__(256) void k_build_map(
    const unsigned* __restrict__ pkey, int* __restrict__ idx_map, int n)
{
    int i = blockIdx.x * blockDim.x + threadIdx.x;
    if (i < n) atomicMax(&idx_map[pkey[i]], i);
}

__device__ __forceinline__ int vquery(const int* __restrict__ idx_map,
                                      const unsigned* __restrict__ pkey,
                                      unsigned cell, int n)
{
    int v = idx_map[cell];
    if (v < 0 || v >= n) return -1;
    return (pkey[v] == cell) ? v : -1;
}

// ---------------- kernel 2 (fused): rulebook + feats->bf16 + W-frags(BN-scaled) ----
// Block-range split: [0,RB) rulebook, [RB,RB+CVT) cvt, [RB+CVT,RB+CVT+27) wcvt.
// wcvt folds the BN scale into the bf16 W fragments and emits sh_all[6][32]
// (full shift: (bias-mean)*sc+beta) for the conv epilogue.
__global__ __launch_bounds__(256) void k_prep(
    const unsigned* __restrict__ pkey, const int* __restrict__ idx_map,
    int* __restrict__ roff,
    const float* __restrict__ feats, unsigned short* __restrict__ xbf,
    const float* __restrict__ Wk, uint4* __restrict__ Bfg,
    const float* __restrict__ bias, const float* __restrict__ gamma,
    const float* __restrict__ beta, const float* __restrict__ mean,
    const float* __restrict__ var, float* __restrict__ sh_all,
    unsigned short* __restrict__ z0, unsigned short* __restrict__ z1,
    unsigned short* __restrict__ z2, int n)
{
    int RB = (n + 255) >> 8;
    int CVT = ((n * NC / 8) + 255) >> 8;
    int bx = blockIdx.x;

    if (bx < RB) {                       // ---- rulebook: roff[9][n] byte offsets ----
        int i = bx * 256 + threadIdx.x;
        if (i >= n) return;
        unsigned key = pkey[i];
        unsigned x = key % CW;
        unsigned y = (key / CW) % CH;
        roff[4 * n + i] = idx_map[key] * 64;   // own cell: cleared+built, trusted
        #pragma unroll
        for (int k = 0; k < 9; ++k) {
            if (k == 4) continue;
            int dy = k / 3 - 1, dx = k % 3 - 1;
            int ny = (int)y + dy, nx = (int)x + dx;
            int nb = -1;
            if (ny >= 0 && ny < CH && nx >= 0 && nx < CW)
                nb = vquery(idx_map, pkey, key + dy * CW + dx, n);
            roff[k * n + i] = (nb >= 0) ? nb * 64 : -1;
        }
    } else if (bx < RB + CVT) {          // ---- feats f32 -> bf16 --------------------
        int i = ((bx - RB) * 256 + threadIdx.x) * 8;
        if (i + 8 <= n * NC) {
            float4 a0 = *(const float4*)(feats + i);
            float4 a1 = *(const float4*)(feats + i + 4);
            uint4 r;
            r.x = pk2(a0.x, a0.y); r.y = pk2(a0.z, a0.w);
            r.z = pk2(a1.x, a1.y); r.w = pk2(a1.z, a1.w);
            *(uint4*)(xbf + i) = r;
        }
    } else {                             // ---- W*sc -> bf16 frags + sh + zero rows --
        int wb = bx - RB - CVT;
        if (wb == 0 && threadIdx.x < 12) {
            uint4 z = make_uint4(0, 0, 0, 0);
            int tt = threadIdx.x;
            if (tt < 4)       ((uint4*)z0)[tt] = z;
            else if (tt < 8)  ((uint4*)z1)[tt - 4] = z;
            else              ((uint4*)z2)[tt - 8] = z;
        }
        int t = wb * 256 + threadIdx.x;
        if (t >= 6 * 9 * 2 * 64) return;
        int l = t & 63, h = (t >> 6) & 1;
        int rest = t >> 7;
        int k = rest % 9, layer = rest / 9;
        int o = l & 31;
        int lo = layer * 32 + o;
        float scv = gamma[lo] * rsqrtf(var[lo] + EPSV);
        if (k == 0 && h == 0 && l < 32)
            sh_all[lo] = (bias[lo] - mean[lo]) * scv + beta[lo];
        int c0 = h * 16 + 8 * (l >> 5);
        const float* wp = Wk + (size_t)layer * 9216 + k * 1024 + o;   // [c][o]
        uint4 r;
        r.x = pk2(wp[(c0 + 0) * 32] * scv, wp[(c0 + 1) * 32] * scv);
        r.y = pk2(wp[(c0 + 2) * 32] * scv, wp[(c0 + 3) * 32] * scv);
        r.z = pk2(wp[(c0 + 4) * 32] * scv, wp[(c0 + 5) * 32] * scv);
        r.w = pk2(wp[(c0 + 6) * 32] * scv, wp[(c0 + 7) * 32] * scv);
        Bfg[t] = r;
    }
}

// ---------------- kernel 4: gather-K 32x32x16 MFMA conv (SWAPPED operands) ---------
// acc = mfma(Wfrag, Xfrag): A/B 32x32x16 lane layouts are symmetric (lane l <->
// row/col l&31, k-slice 8*(l>>5)), so W frags (A) and the X gather (B) are the
// SAME loads as before; only arg order + epilogue flip. D: col = point = l&31,
// row = channel = (r&3)+8*(r>>2)+4*h5 -> lane owns 1 point x 16 channels in 4
// groups of 4 consecutive -> 4x8B stores + 4x8B idn loads (was 16x2B + 16x2B).
// BN scale pre-folded into W frags; shift via broadcast float4 from sh_all.
template<bool ADD_ID, bool F32OUT>
__global__ __launch_bounds__(256, 6) void k_conv(
    const unsigned short* __restrict__ in,   // bf16 [n+1][32], row n = zeros
    const unsigned short* __restrict__ idn,  // bf16 [n][32]
    void* __restrict__ outv,                 // bf16 or f32 [n][32]
    const uint4* __restrict__ Bf,            // [9][2][64] W-frags (BN-scaled)
    const float* __restrict__ sh,            // [32] BN shift (this layer)
    const int* __restrict__ roff, int n)
{
    int l = threadIdx.x & 63, wv = threadIdx.x >> 6;
    int q = l & 31, h5 = l >> 5;

    int ntile = (n + 31) >> 5;
    int tile = blockIdx.x * 4 + wv;
    if (tile >= ntile) return;

    const int zoff = n * 64;
    const char* inB = (const char*)in;

    int p0 = tile << 5;
    int pr = p0 + q;
    bool rowok = pr < n;
    int prc = rowok ? pr : n - 1;

    int rk[9];
    #pragma unroll
    for (int k = 0; k < 9; ++k) rk[k] = roff[(size_t)k * n + prc];

    f32x16 acc = {0.f,0.f,0.f,0.f,0.f,0.f,0.f,0.f,0.f,0.f,0.f,0.f,0.f,0.f,0.f,0.f};

    #pragma unroll
    for (int g = 0; g < 3; ++g) {
        bool act[3];
        U16 a0[3], a1[3];
        #pragma unroll
        for (int j = 0; j < 3; ++j) {
            int k = g * 3 + j;
            act[j] = __any(rk[k] >= 0);
            if (act[j]) {
                int off = (rowok && rk[k] >= 0) ? rk[k] : zoff;
                const char* ap = inB + off + h5 * 16;
                a0[j].u = *(const uint4*)(ap);        // chans h5*8    ..+8 (K-half 0)
                a1[j].u = *(const uint4*)(ap + 32);   // chans 16+h5*8 ..+8 (K-half 1)
            }
        }
        #pragma unroll
        for (int j = 0; j < 3; ++j) {
            int k = g * 3 + j;
            if (act[j]) {
                U16 b0, b1;
                b0.u = Bf[(k * 2 + 0) * 64 + l];
                b1.u = Bf[(k * 2 + 1) * 64 + l];
                acc = __builtin_amdgcn_mfma_f32_32x32x16_bf16(b0.v, a0[j].v, acc, 0, 0, 0);
                acc = __builtin_amdgcn_mfma_f32_32x32x16_bf16(b1.v, a1[j].v, acc, 0, 0, 0);
            }
        }
    }

    // epilogue: lane owns point pr, channels {g*8+4*h5 .. +4} for g=0..3
    if (rowok) {
        #pragma unroll
        for (int g = 0; g < 4; ++g) {
            int ch = g * 8 + 4 * h5;
            float4 s4 = *(const float4*)(sh + ch);
            float y0 = acc[g * 4 + 0] + s4.x;
            float y1 = acc[g * 4 + 1] + s4.y;
            float y2 = acc[g * 4 + 2] + s4.z;
            float y3 = acc[g * 4 + 3] + s4.w;
            if (ADD_ID) {
                uint2 iv = *(const uint2*)(idn + (size_t)pr * 32 + ch);
                y0 += bfl(iv.x); y1 += bfh(iv.x);
                y2 += bfl(iv.y); y3 += bfh(iv.y);
            }
            y0 = fmaxf(y0, 0.f); y1 = fmaxf(y1, 0.f);
            y2 = fmaxf(y2, 0.f); y3 = fmaxf(y3, 0.f);
            if (F32OUT) {
                *(float4*)((float*)outv + (size_t)pr * 32 + ch) =
                    make_float4(y0, y1, y2, y3);
            } else {
                uint2 r;
                r.x = pk2(y0, y1); r.y = pk2(y2, y3);
                *(uint2*)((unsigned short*)outv + (size_t)pr * 32 + ch) = r;
            }
        }
    }
}

extern "C" void kernel_launch(void* const* d_in, const int* in_sizes, int n_in,
                              void* d_out, int out_size, void* d_ws, size_t ws_size,
                              hipStream_t stream)
{
    const float* feats = (const float*)d_in[0];
    const float* Wk    = (const float*)d_in[1];  // [3][2][9][32][32]
    const float* bias  = (const float*)d_in[2];
    const float* gamma = (const float*)d_in[3];
    const float* beta  = (const float*)d_in[4];
    const float* mean  = (const float*)d_in[5];
    const float* var   = (const float*)d_in[6];
    const int* cb = (const int*)d_in[7];
    const int* cy = (const int*)d_in[8];
    const int* cx = (const int*)d_in[9];
    float* out = (float*)d_out;
    int n = in_sizes[0] / NC;

    char* ws = (char*)d_ws;
    int*            idx_map = (int*)(ws + 0);                   // 33,177,600 B
    unsigned*       pkey    = (unsigned*)(ws + 33177600);       //    800,000 B
    int*            roff    = (int*)(ws + 33977600);            //  7,200,000 B
    uint4*          Bfg     = (uint4*)(ws + 41177600);          //    110,592 B
    float*          sh_all  = (float*)(ws + 41288192);          //        768 B
    unsigned short* xbf     = (unsigned short*)(ws + 41288960); // 12,800,064 B
    unsigned short* tmpbf   = (unsigned short*)(ws + 54089024); // 12,800,064 B
    unsigned short* hb      = (unsigned short*)(ws + 66889088); // 12,800,064 B

    int RB  = (n + 255) / 256;
    int CVT = ((n * NC / 8) + 255) / 256;
    k_clear<<<RB, 256, 0, stream>>>(cb, cy, cx, idx_map, pkey, n);
    k_build_map<<<RB, 256, 0, stream>>>(pkey, idx_map, n);
    k_prep<<<RB + CVT + 27, 256, 0, stream>>>(
        pkey, idx_map, roff, feats, xbf, Wk, Bfg,
        bias, gamma, beta, mean, var, sh_all,
        xbf + (size_t)n * 32, tmpbf + (size_t)n * 32, hb + (size_t)n * 32, n);

    const int ntile = (n + 31) / 32;
    const int G = (ntile + 3) / 4;   // one tile per wave, single pass
    const int BSZ = 9 * 2 * 64;      // uint4s per layer of Bfg

    k_conv<false, false><<<G, 256, 0, stream>>>(xbf, nullptr, tmpbf,
        Bfg + 0 * BSZ, sh_all + 0,   roff, n);
    k_conv<true,  false><<<G, 256, 0, stream>>>(tmpbf, xbf, hb,
        Bfg + 1 * BSZ, sh_all + 32,  roff, n);
    k_conv<false, false><<<G, 256, 0, stream>>>(hb, nullptr, tmpbf,
        Bfg + 2 * BSZ, sh_all + 64,  roff, n);
    k_conv<true,  false><<<G, 256, 0, stream>>>(tmpbf, hb, xbf,
        Bfg + 3 * BSZ, sh_all + 96,  roff, n);
    k_conv<false, false><<<G, 256, 0, stream>>>(xbf, nullptr, tmpbf,
        Bfg + 4 * BSZ, sh_all + 128, roff, n);
    k_conv<true,  true><<<G, 256, 0, stream>>>(tmpbf, xbf, out,
        Bfg + 5 * BSZ, sh_all + 160, roff, n);
}